// Round 4
// baseline (273.169 us; speedup 1.0000x reference)
//
#include <hip/hip_runtime.h>
#include <cstddef>
#include <cstdint>

// ---------------------------------------------------------------------------
// Pipeline (6 launches):
//   prep (weight repack) -> kv_prep (kv LN + k/v proj, per-b)
//   -> conv1+GDN1 fused (4-row blocks, grid 512, 2 blk/CU)
//   -> conv2+GDN2 fused (LDS-staged weights, 4-row x 512-thread, grid 256)
//   -> conv3 3x3 (LDS-staged weights) -> attn v5 (q-LN carried in regs).
// ---------------------------------------------------------------------------

typedef __bf16 bf16x8 __attribute__((ext_vector_type(8)));
typedef float floatx4 __attribute__((ext_vector_type(4)));
typedef unsigned short ushortT;
typedef unsigned short ushort8v __attribute__((ext_vector_type(8)));

#if __has_builtin(__builtin_amdgcn_exp2f)
#define EXP2F(x) __builtin_amdgcn_exp2f(x)
#else
#define EXP2F(x) exp2f(x)
#endif
#if __has_builtin(__builtin_amdgcn_rcpf)
#define RCPF(x) __builtin_amdgcn_rcpf(x)
#else
#define RCPF(x) (1.f / (x))
#endif

__device__ __forceinline__ ushortT f2bf(float f) {
  unsigned u = __builtin_bit_cast(unsigned, f);
  unsigned r = (u + 0x7FFFu + ((u >> 16) & 1u)) >> 16;
  return (ushortT)r;
}
__device__ __forceinline__ float bf2f(ushortT u) {
  return __builtin_bit_cast(float, ((unsigned)u) << 16);
}

// ---- workspace layout (float-slot offsets) ----
static constexpr size_t OFF_X2BF = 4194304;    // gdn1 out bf16 [b][4][256][128]
static constexpr size_t OFF_X3BF = 9437184;    // gdn2 out bf16 (64,256,128)
static constexpr size_t OFF_QRAW = 10485760;   // conv3 out bf16 (64,256,192)
static constexpr size_t OFF_WBQ  = 21299200;   // bf16 128x192 (scaled by c)
static constexpr size_t OFF_WBK  = 21311488;   // bf16 128x192 (scaled by c)
static constexpr size_t OFF_WBV  = 21323776;   // bf16 192x192
static constexpr size_t OFF_WBO  = 21342208;   // bf16 192x192
static constexpr size_t OFF_WT2  = 26079232;   // bf16 conv2 slabs [200][2048]
static constexpr size_t OFF_WT3  = 26284032;   // bf16 conv3 slabs [108][2048]
static constexpr size_t OFF_WC1  = 26394624;   // bf16 conv1 slabs [5][128][32]
static constexpr size_t OFF_GB1  = 26406912;   // bf16 gamma1 128x128
static constexpr size_t OFF_GB2  = 26415104;   // bf16 gamma2 128x128
// kv_prep outputs live in the (unused) low region:
static constexpr size_t OFF_KP   = 0;          // f32  [64][32][128]
static constexpr size_t OFF_VT   = 262144;     // bf16 [64][192][32]

// 5x5 s2 p2 polyphase tap tables (tap id = kh*5+kw); HW-verified via conv2.
__device__ __constant__ int d_TWI2[4][9] = {{ 0, 2, 4,10,12,14,20,22,24},
                                            { 1, 3,11,13,21,23, 0, 0, 0},
                                            { 5, 7, 9,15,17,19, 0, 0, 0},
                                            { 6, 8,16,18, 0, 0, 0, 0, 0}};
__device__ __constant__ int d_NT2[4] = {9, 6, 6, 4};

// ---------------------------------------------------------------------------
// fused prep: all weight repacks/casts in one launch, block-range dispatch.
// ---------------------------------------------------------------------------
__device__ void dev_convw3(const float* w, ushortT* wt, int mode, int total,
                           int idx) {
  if (idx >= total) return;
  int j    = idx & 7;
  int om   = (idx >> 3) & 63;
  int kg   = (idx >> 9) & 3;
  int slab = idx >> 11;
  int mt, s, tap, T;
  if (mode == 0) {
    int ph;
    if (slab < 72) ph = 0; else if (slab < 120) ph = 1;
    else if (slab < 168) ph = 2; else ph = 3;
    const int st[4] = {0, 72, 120, 168};
    const int ns[4] = {36, 24, 24, 16};
    int rel = slab - st[ph];
    mt = rel / ns[ph]; s = rel % ns[ph];
    tap = d_TWI2[ph][s >> 2]; T = 25;
  } else {
    mt = slab / 36; s = slab % 36; tap = s >> 2; T = 9;
  }
  int cc = s & 3;
  int c  = cc * 32 + kg * 8 + j;
  int oc = mt * 64 + om;
  wt[idx] = f2bf(w[(size_t)(oc * 128 + c) * T + tap]);
}

__device__ void dev_convw1(const float* w, ushortT* wt, int idx) {
  if (idx >= 20480) return;
  int k    = idx & 31;
  int oc   = (idx >> 5) & 127;
  int slab = idx >> 12;
  int ph, i;
  if (slab < 2) { ph = 0; i = slab; } else { ph = slab - 1; i = 0; }
  int kg = k >> 3, jj = k & 7;
  int tidx = i * 8 + jj;
  float val = 0.f;
  if (kg < 3 && tidx < d_NT2[ph]) {
    int tap = d_TWI2[ph][tidx];
    val = w[(size_t)(oc * 3 + kg) * 25 + tap];
  }
  wt[idx] = f2bf(val);
}

__device__ void dev_wcast(const float* w, ushortT* wb, int total, float scale,
                          int idx) {
  if (idx < total) wb[idx] = f2bf(w[idx] * scale);
}

__global__ __launch_bounds__(256) void prep_kernel(
    const float* __restrict__ conv2_w, ushortT* __restrict__ wt2,
    const float* __restrict__ conv3_w, ushortT* __restrict__ wt3,
    const float* __restrict__ conv1_w, ushortT* __restrict__ wc1,
    const float* __restrict__ Wq, ushortT* __restrict__ wbq,
    const float* __restrict__ Wk, ushortT* __restrict__ wbk,
    const float* __restrict__ Wv, ushortT* __restrict__ wbv,
    const float* __restrict__ out_w, ushortT* __restrict__ wbo,
    const float* __restrict__ gamma1, ushortT* __restrict__ gb1,
    const float* __restrict__ gamma2, ushortT* __restrict__ gb2) {
  constexpr float C2LE = 2.88539008177792681f;   // 2*log2(e)
  int blk = blockIdx.x, tid = threadIdx.x;
  if (blk < 1600)      dev_convw3(conv2_w, wt2, 0, 409600, blk * 256 + tid);
  else if (blk < 2464) dev_convw3(conv3_w, wt3, 1, 221184, (blk - 1600) * 256 + tid);
  else if (blk < 2544) dev_convw1(conv1_w, wc1, (blk - 2464) * 256 + tid);
  else if (blk < 2640) dev_wcast(Wq, wbq, 24576, C2LE, (blk - 2544) * 256 + tid);
  else if (blk < 2736) dev_wcast(Wk, wbk, 24576, C2LE, (blk - 2640) * 256 + tid);
  else if (blk < 2880) dev_wcast(Wv, wbv, 36864, 1.f, (blk - 2736) * 256 + tid);
  else if (blk < 3024) dev_wcast(out_w, wbo, 36864, 1.f, (blk - 2880) * 256 + tid);
  else if (blk < 3088) dev_wcast(gamma1, gb1, 16384, 1.f, (blk - 3024) * 256 + tid);
  else                 dev_wcast(gamma2, gb2, 16384, 1.f, (blk - 3088) * 256 + tid);
}

// ---------------------------------------------------------------------------
// conv1+GDN1 fused: 4 output rows per block, grid 512 -> 2 blocks/CU.
// ---------------------------------------------------------------------------
__global__ __launch_bounds__(256, 2) void conv1_gdn_kernel(
    const float* __restrict__ x, const ushortT* __restrict__ wc1,
    const float* __restrict__ bias, const ushortT* __restrict__ gb1,
    const float* __restrict__ beta1, ushortT* __restrict__ outb) {
  int b  = blockIdx.x >> 3;
  int yg = blockIdx.x & 7;
  int y0 = yg * 4;

  int wave = threadIdx.x >> 6;
  int lane = threadIdx.x & 63;
  int ln15 = lane & 15;
  int kg   = lane >> 4;
  int tid  = threadIdx.x;

  __shared__ ushortT smem[28416];
  ushortT* simg = smem;
  ushortT* sA   = smem + 2816;

  for (int j = tid; j < 1408; j += 256) ((unsigned*)simg)[j] = 0u;
  __syncthreads();

  int ihBase = 2 * y0 - 2;
  const float* xb = x + (size_t)b * 3 * 4096;
  for (int j = tid; j < 576; j += 256) {
    int q = j & 15;
    int rr = j >> 4;
    int c = rr / 12, ihl = rr % 12;
    int ih = ihBase + ihl;
    if (ih >= 0 && ih < 64) {
      float4 v = *(const float4*)&xb[c * 4096 + ih * 64 + q * 4];
      int pr = ih & 1, u = ih >> 1;
      int lr = u - y0 + 1;
      int base0 = ((pr * 2 + 0) * 3 + c) * 216 + lr * 36;
      int base1 = ((pr * 2 + 1) * 3 + c) * 216 + lr * 36;
      simg[base0 + 2 * q + 1] = f2bf(v.x);
      simg[base1 + 2 * q + 1] = f2bf(v.y);
      simg[base0 + 2 * q + 2] = f2bf(v.z);
      simg[base1 + 2 * q + 2] = f2bf(v.w);
    }
  }
  for (int j = tid; j < 2560; j += 256) {
    int chunk = j & 3, row = j >> 2;
    uint4 v = *(const uint4*)&wc1[row * 32 + chunk * 8];
    *(uint4*)&sA[row * 40 + chunk * 8] = v;
  }
  __syncthreads();

  constexpr int TDR[4][9] = {{-1,-1,-1, 0, 0, 0, 1, 1, 1},
                             {-1,-1, 0, 0, 1, 1, 0, 0, 0},
                             {-1,-1,-1, 0, 0, 0, 0, 0, 0},
                             {-1,-1, 0, 0, 0, 0, 0, 0, 0}};
  constexpr int TDC[4][9] = {{-1, 0, 1,-1, 0, 1,-1, 0, 1},
                             {-1, 0,-1, 0,-1, 0, 0, 0, 0},
                             {-1, 0, 1,-1, 0, 1, 0, 0, 0},
                             {-1, 0,-1, 0, 0, 0, 0, 0, 0}};
  constexpr int NT[4]  = {9, 6, 6, 4};
  constexpr int NM[4]  = {2, 1, 1, 1};
  constexpr int SB[4]  = {0, 2, 3, 4};

  ushort8v Bf[2][5];
  #pragma unroll
  for (int ntl = 0; ntl < 2; ++ntl) {
    int ntg = wave * 2 + ntl;
    int yloc = ntg >> 1;
    int xx = (ntg & 1) * 16 + ln15;
    int lbase = (yloc + 1) * 36 + xx + 1 + kg * 216;
    #pragma unroll
    for (int ph = 0; ph < 4; ++ph) {
      int pbase = ph * 648 + lbase;
      #pragma unroll
      for (int i = 0; i < 2; ++i) {
        if (i < NM[ph]) {
          ushort8v bv;
          #pragma unroll
          for (int j = 0; j < 8; ++j) {
            int tidx = i * 8 + j;
            if (tidx >= NT[ph]) tidx = 0;
            int off = TDR[ph][tidx] * 36 + TDC[ph][tidx];
            bv[j] = simg[pbase + off];
          }
          Bf[ntl][SB[ph] + i] = bv;
        }
      }
    }
  }

  ushort4 xq[8][2];
  #pragma unroll
  for (int m = 0; m < 8; ++m) {
    bf16x8 Af[5];
    #pragma unroll
    for (int s = 0; s < 5; ++s)
      Af[s] = *(const bf16x8*)&sA[(s * 128 + m * 16 + ln15) * 40 + kg * 8];
    int oc0 = m * 16 + kg * 4;
    float4 bv = *(const float4*)&bias[oc0];
    #pragma unroll
    for (int ntl = 0; ntl < 2; ++ntl) {
      floatx4 acc = (floatx4)0.f;
      #pragma unroll
      for (int s = 0; s < 5; ++s)
        acc = __builtin_amdgcn_mfma_f32_16x16x32_bf16(
            Af[s], __builtin_bit_cast(bf16x8, Bf[ntl][s]), acc, 0, 0, 0);
      ushort4 o4 = {f2bf(acc[0] + bv.x), f2bf(acc[1] + bv.y),
                    f2bf(acc[2] + bv.z), f2bf(acc[3] + bv.w)};
      xq[m][ntl] = o4;
    }
  }
  __syncthreads();

  for (int j = tid; j < 2048; j += 256) {
    int row = j >> 4, ch = j & 15;
    *(uint4*)&smem[row * 136 + ch * 8] = *(const uint4*)&gb1[row * 128 + ch * 8];
  }
  __syncthreads();

  const int sxbase = 17408 + wave * 2176;
  #pragma unroll
  for (int q = 0; q < 2; ++q) {
    #pragma unroll
    for (int m = 0; m < 8; ++m) {
      ushort4 xv = xq[m][q];
      float f0 = bf2f(xv.x), f1 = bf2f(xv.y), f2 = bf2f(xv.z), f3 = bf2f(xv.w);
      ushort4 s4 = {f2bf(f0 * f0), f2bf(f1 * f1), f2bf(f2 * f2), f2bf(f3 * f3)};
      *(ushort4*)&smem[sxbase + ln15 * 136 + m * 16 + kg * 4] = s4;
    }
    int ntg = wave * 2 + q;
    int y = y0 + (ntg >> 1);
    int xx = (ntg & 1) * 16 + ln15;
    int ph = ((y & 1) << 1) | (xx & 1);
    size_t dstbase = (((size_t)b * 4 + ph) * 256 + (y >> 1) * 16 + (xx >> 1)) * 128;
    #pragma unroll
    for (int dt = 0; dt < 8; ++dt) {
      floatx4 acc = (floatx4)0.f;
      #pragma unroll
      for (int k0 = 0; k0 < 4; ++k0) {
        bf16x8 ga = *(const bf16x8*)&smem[(dt * 16 + ln15) * 136 + k0 * 32 + kg * 8];
        bf16x8 xbv = *(const bf16x8*)&smem[sxbase + ln15 * 136 + k0 * 32 + kg * 8];
        acc = __builtin_amdgcn_mfma_f32_16x16x32_bf16(ga, xbv, acc, 0, 0, 0);
      }
      int d0 = dt * 16 + kg * 4;
      float4 bt = *(const float4*)&beta1[d0];
      ushort4 xv = xq[dt][q];
      ushort4 o4;
      o4.x = f2bf(bf2f(xv.x) * rsqrtf(acc[0] + bt.x));
      o4.y = f2bf(bf2f(xv.y) * rsqrtf(acc[1] + bt.y));
      o4.z = f2bf(bf2f(xv.z) * rsqrtf(acc[2] + bt.z));
      o4.w = f2bf(bf2f(xv.w) * rsqrtf(acc[3] + bt.w));
      *(ushort4*)&outb[dstbase + d0] = o4;
    }
  }
}

// ---------------------------------------------------------------------------
// conv2+GDN2 fused, v3: LDS-staged weights. 4 rows x 16 px x 128 oc per
// block, 512 threads, grid 256. Per phase: weights staged in chunks of 8
// slabs (4 per oc-half) into sW; all 8 waves consume from LDS -> 8x less L2.
// Register prefetch of next chunk overlaps MFMA.
// LDS: simg [0,14688) [6][18][136]; sW [14688,31072) 8x2048; sX2 overlays sW.
// ---------------------------------------------------------------------------
__global__ __launch_bounds__(512, 2) void conv2_gdn_kernel(
    const ushortT* __restrict__ X, const ushortT* __restrict__ Wt,
    const float* __restrict__ bias, const ushortT* __restrict__ gb2,
    const float* __restrict__ beta2, ushortT* __restrict__ outb) {
  int b  = blockIdx.x >> 2;
  int rs = blockIdx.x & 3;
  int r0 = rs * 4;

  int tid  = threadIdx.x;
  int wave = tid >> 6;
  int lane = tid & 63;
  int ln15 = lane & 15;
  int kg   = lane >> 4;
  int wrow  = wave & 3;
  int whalf = wave >> 2;

  __shared__ ushortT smem[31072];
  ushortT* simg = smem;
  ushortT* sW   = smem + 14688;
  ushortT* sX2  = smem + 14688;   // overlays sW after the conv loop

  floatx4 acc[4];
  #pragma unroll
  for (int m = 0; m < 4; ++m) acc[m] = (floatx4)0.f;

  constexpr int NS2[4]      = {36, 24, 24, 16};
  constexpr int PHSTART2[4] = {0, 72, 120, 168};
  constexpr int TDR_2[4][9] = {{-1,-1,-1, 0, 0, 0, 1, 1, 1},
                               {-1,-1, 0, 0, 1, 1, 0, 0, 0},
                               {-1,-1,-1, 0, 0, 0, 0, 0, 0},
                               {-1,-1, 0, 0, 0, 0, 0, 0, 0}};
  constexpr int TDC_2[4][9] = {{-1, 0, 1,-1, 0, 1,-1, 0, 1},
                               {-1, 0,-1, 0,-1, 0, 0, 0, 0},
                               {-1, 0, 1,-1, 0, 1, 0, 0, 0},
                               {-1, 0,-1, 0, 0, 0, 0, 0, 0}};

  const int aoff = kg * 512 + ln15 * 8;

  #pragma unroll
  for (int ph = 0; ph < 4; ++ph) {
    const int NS = NS2[ph];
    const int P  = PHSTART2[ph];

    __syncthreads();   // prior phase LDS reads (simg + sW) complete
    const ushortT* Xb = X + (((size_t)b * 4 + ph) * 256) * 128;
    for (int idx = tid; idx < 1728; idx += 512) {
      int chunk = idx & 15;
      int pix = idx >> 4;
      int row = pix / 18, colm = pix - row * 18;
      int i = r0 - 1 + row, j = colm - 1;
      uint4 v = {0u, 0u, 0u, 0u};
      if (i >= 0 && i < 16 && j >= 0 && j < 16)
        v = *(const uint4*)(Xb + ((size_t)(i * 16 + j)) * 128 + chunk * 8);
      *(uint4*)&simg[(row * 18 + colm) * 136 + chunk * 8] = v;
    }

    // prefetch chunk 0: 8 slabs (slot = mt*4 + i), thread covers 4 uint4
    uint4 creg[4];
    #pragma unroll
    for (int j = 0; j < 4; ++j) {
      int u = tid + j * 512;
      int slot = u >> 8;
      int off = (u & 255) * 8;
      creg[j] = *(const uint4*)(Wt +
          (size_t)(P + (slot >> 2) * NS + (slot & 3)) * 2048 + off);
    }

    for (int c0 = 0; c0 < NS; c0 += 4) {
      __syncthreads();   // simg staged (1st iter) / prior chunk MFMA done
      #pragma unroll
      for (int j = 0; j < 4; ++j) {
        int u = tid + j * 512;
        int slot = u >> 8;
        int off = (u & 255) * 8;
        *(uint4*)&sW[slot * 2048 + off] = creg[j];
      }
      if (c0 + 4 < NS) {
        #pragma unroll
        for (int j = 0; j < 4; ++j) {
          int u = tid + j * 512;
          int slot = u >> 8;
          int off = (u & 255) * 8;
          creg[j] = *(const uint4*)(Wt +
              (size_t)(P + (slot >> 2) * NS + c0 + 4 + (slot & 3)) * 2048 + off);
        }
      }
      __syncthreads();   // sW visible
      #pragma unroll
      for (int i = 0; i < 4; ++i) {
        int s = c0 + i;
        int t = s >> 2;
        int cc = (s & 3) * 32;
        int dr = TDR_2[ph][t];
        int dc = TDC_2[ph][t];
        bf16x8 bfr = *(const bf16x8*)&simg[((wrow + dr + 1) * 18 +
                                            (ln15 + dc + 1)) * 136 + cc + kg * 8];
        const ushortT* wsl = &sW[(whalf * 4 + i) * 2048 + aoff];
        #pragma unroll
        for (int m = 0; m < 4; ++m) {
          bf16x8 af = *(const bf16x8*)&wsl[m * 128];
          acc[m] = __builtin_amdgcn_mfma_f32_16x16x32_bf16(af, bfr, acc[m], 0, 0, 0);
        }
      }
    }
  }

  __syncthreads();   // last chunk MFMA reads done before sX2 overlays sW

  // ---- GDN2 in-block ----
  ushort4 xq2[4];
  #pragma unroll
  for (int m = 0; m < 4; ++m) {
    int mg = whalf * 64 + m * 16 + kg * 4;
    float4 bv = *(const float4*)&bias[mg];
    ushort4 o4 = {f2bf(acc[m][0] + bv.x), f2bf(acc[m][1] + bv.y),
                  f2bf(acc[m][2] + bv.z), f2bf(acc[m][3] + bv.w)};
    xq2[m] = o4;
    float f0 = bf2f(o4.x), f1 = bf2f(o4.y), f2 = bf2f(o4.z), f3 = bf2f(o4.w);
    ushort4 s4 = {f2bf(f0 * f0), f2bf(f1 * f1), f2bf(f2 * f2), f2bf(f3 * f3)};
    *(ushort4*)&sX2[(wrow * 16 + ln15) * 136 + mg] = s4;
  }
  __syncthreads();

  int p = (r0 + wrow) * 16 + ln15;
  size_t obase = ((size_t)b * 256 + p) * 128;
  #pragma unroll
  for (int dti = 0; dti < 4; ++dti) {
    int dt = whalf * 4 + dti;
    floatx4 nacc = (floatx4)0.f;
    #pragma unroll
    for (int k0 = 0; k0 < 4; ++k0) {
      bf16x8 ga = *(const bf16x8*)&gb2[(size_t)(dt * 16 + ln15) * 128 + k0 * 32 + kg * 8];
      bf16x8 xbv = *(const bf16x8*)&sX2[(wrow * 16 + ln15) * 136 + k0 * 32 + kg * 8];
      nacc = __builtin_amdgcn_mfma_f32_16x16x32_bf16(ga, xbv, nacc, 0, 0, 0);
    }
    int d0 = dt * 16 + kg * 4;
    float4 bt = *(const float4*)&beta2[d0];
    ushort4 xv = xq2[dti];
    ushort4 o4;
    o4.x = f2bf(bf2f(xv.x) * rsqrtf(nacc[0] + bt.x));
    o4.y = f2bf(bf2f(xv.y) * rsqrtf(nacc[1] + bt.y));
    o4.z = f2bf(bf2f(xv.z) * rsqrtf(nacc[2] + bt.z));
    o4.w = f2bf(bf2f(xv.w) * rsqrtf(nacc[3] + bt.w));
    *(ushort4*)&outb[obase + d0] = o4;
  }
}

// ---------------------------------------------------------------------------
// conv3 MFMA implicit GEMM (3x3 s1), v2: LDS-staged weights (chunks of 8
// slabs shared by the 4 waves), 4-row split, 2 blocks/CU, bf16 out.
// LDS: simg [0,14688); sW [14688,31072).
// ---------------------------------------------------------------------------
__global__ __launch_bounds__(256, 2) void conv3_mfma_kernel(
    const ushortT* __restrict__ X,
    const ushortT* __restrict__ Wt,
    const float* __restrict__ bias,
    ushortT* __restrict__ outb) {
  constexpr int OC  = 192;
  constexpr int NMT = 3;

  int b   = blockIdx.x / (NMT * 4);
  int rem = blockIdx.x % (NMT * 4);
  int mt  = rem >> 2;
  int rs  = rem & 3;
  int r0  = rs * 4;

  int tid  = threadIdx.x;
  int wave = tid >> 6;
  int lane = tid & 63;
  int ln15 = lane & 15;
  int kg   = lane >> 4;

  __shared__ ushortT smem[31072];
  ushortT* simg = smem;
  ushortT* sW   = smem + 14688;

  floatx4 acc[4];
  #pragma unroll
  for (int m = 0; m < 4; ++m) acc[m] = (floatx4)0.f;

  constexpr int TDR_3[9] = {-1,-1,-1, 0, 0, 0, 1, 1, 1};
  constexpr int TDC_3[9] = {-1, 0, 1,-1, 0, 1,-1, 0, 1};

  const int aoff = kg * 512 + ln15 * 8;

  const ushortT* Xb = X + ((size_t)b * 256) * 128;
  for (int idx = tid; idx < 1728; idx += 256) {
    int chunk = idx & 15;
    int pix = idx >> 4;
    int row = pix / 18, colm = pix - row * 18;
    int i = r0 - 1 + row, j = colm - 1;
    uint4 v = {0u, 0u, 0u, 0u};
    if (i >= 0 && i < 16 && j >= 0 && j < 16)
      v = *(const uint4*)(Xb + ((size_t)(i * 16 + j)) * 128 + chunk * 8);
    *(uint4*)&simg[(row * 18 + colm) * 136 + chunk * 8] = v;
  }

  // prefetch chunk 0 (slabs mt*36 + [0,8)); thread tid covers offset tid*8
  uint4 creg[8];
  #pragma unroll
  for (int j = 0; j < 8; ++j)
    creg[j] = *(const uint4*)(Wt + (size_t)(mt * 36 + j) * 2048 + tid * 8);

  for (int c0 = 0; c0 < 36; c0 += 8) {
    int cn = 36 - c0; if (cn > 8) cn = 8;
    __syncthreads();   // simg staged (1st iter) / prior chunk MFMA done
    #pragma unroll
    for (int j = 0; j < 8; ++j)
      if (j < cn) *(uint4*)&sW[j * 2048 + tid * 8] = creg[j];
    if (c0 + 8 < 36) {
      int nn = 36 - (c0 + 8); if (nn > 8) nn = 8;
      #pragma unroll
      for (int j = 0; j < 8; ++j)
        if (j < nn)
          creg[j] = *(const uint4*)(Wt + (size_t)(mt * 36 + c0 + 8 + j) * 2048 + tid * 8);
    }
    __syncthreads();   // sW visible
    #pragma unroll
    for (int i = 0; i < 8; ++i) {
      if (i < cn) {
        int s = c0 + i;
        int t = s >> 2;
        int cc = (s & 3) * 32;
        int lrow = wave + TDR_3[t] + 1;
        int lcol = ln15 + TDC_3[t] + 1;
        bf16x8 bfr = *(const bf16x8*)&simg[(lrow * 18 + lcol) * 136 + cc + kg * 8];
        const ushortT* wsl = &sW[i * 2048 + aoff];
        #pragma unroll
        for (int m = 0; m < 4; ++m) {
          bf16x8 af = *(const bf16x8*)&wsl[m * 128];
          acc[m] = __builtin_amdgcn_mfma_f32_16x16x32_bf16(af, bfr, acc[m], 0, 0, 0);
        }
      }
    }
  }

  #pragma unroll
  for (int m = 0; m < 4; ++m) {
    int mg = mt * 64 + m * 16 + kg * 4;
    float4 bv = *(const float4*)&bias[mg];
    int r = r0 + wave;
    int p = r * 16 + ln15;
    ushort4 o4 = {f2bf(acc[m][0] + bv.x), f2bf(acc[m][1] + bv.y),
                  f2bf(acc[m][2] + bv.z), f2bf(acc[m][3] + bv.w)};
    *(ushort4*)&outb[((size_t)b * 256 + p) * OC + mg] = o4;
  }
}

// ---------------------------------------------------------------------------
// kv_prep: per-b (grid 64): stage yg -> kv LN -> kproj (f32, scaled) and
// vproj^T (bf16) to workspace.
// ---------------------------------------------------------------------------
__global__ __launch_bounds__(256) void kv_prep_kernel(
    const float* __restrict__ yg, const float* __restrict__ ln_kv_w,
    const float* __restrict__ ln_kv_b, const ushortT* __restrict__ wbk,
    const ushortT* __restrict__ wbv, float* __restrict__ kp,
    ushortT* __restrict__ vT) {
  __shared__ float skvRaw[32 * 194];
  __shared__ ushortT skv[32 * 200];
  int b = blockIdx.x;
  int tid = threadIdx.x;
  int wave = tid >> 6, lane = tid & 63, ln15 = lane & 15, kg = lane >> 4;

  const float4* yg4 = (const float4*)(yg + (size_t)b * 6144);
  for (int j = tid; j < 1536; j += 256) {
    float4 v = yg4[j];
    int c = j >> 3;
    int t4 = (j & 7) * 4;
    skvRaw[(t4 + 0) * 194 + c] = v.x;
    skvRaw[(t4 + 1) * 194 + c] = v.y;
    skvRaw[(t4 + 2) * 194 + c] = v.z;
    skvRaw[(t4 + 3) * 194 + c] = v.w;
  }
  __syncthreads();
  for (int r = wave; r < 32; r += 4) {
    const float* src = skvRaw + r * 194;
    float v0 = src[lane], v1 = src[lane + 64], v2 = src[lane + 128];
    float s = v0 + v1 + v2;
    float s2 = v0 * v0 + v1 * v1 + v2 * v2;
    #pragma unroll
    for (int off = 32; off; off >>= 1) { s += __shfl_xor(s, off); s2 += __shfl_xor(s2, off); }
    float mean = s * (1.f / 192.f);
    float var = s2 * (1.f / 192.f) - mean * mean;
    float inv = rsqrtf(var + 1e-5f);
    skv[r * 200 + lane]       = f2bf((v0 - mean) * inv * ln_kv_w[lane]       + ln_kv_b[lane]);
    skv[r * 200 + lane + 64]  = f2bf((v1 - mean) * inv * ln_kv_w[lane + 64]  + ln_kv_b[lane + 64]);
    skv[r * 200 + lane + 128] = f2bf((v2 - mean) * inv * ln_kv_w[lane + 128] + ln_kv_b[lane + 128]);
  }
  __syncthreads();
  for (int ti = wave; ti < 40; ti += 4) {
    floatx4 acc = (floatx4)0.f;
    if (ti < 16) {
      int rt = ti >> 3, ct = ti & 7;
      #pragma unroll
      for (int k0 = 0; k0 < 192; k0 += 32) {
        bf16x8 afr = *(const bf16x8*)&skv[(rt * 16 + ln15) * 200 + k0 + kg * 8];
        bf16x8 bfr = *(const bf16x8*)&wbk[((size_t)(ct * 16 + ln15)) * 192 + k0 + kg * 8];
        acc = __builtin_amdgcn_mfma_f32_16x16x32_bf16(afr, bfr, acc, 0, 0, 0);
      }
      #pragma unroll
      for (int r = 0; r < 4; ++r)
        kp[((size_t)b * 32 + rt * 16 + kg * 4 + r) * 128 + ct * 16 + ln15] = acc[r];
    } else {
      int t2 = ti - 16;
      int rt = t2 / 12, ct = t2 % 12;
      #pragma unroll
      for (int k0 = 0; k0 < 192; k0 += 32) {
        bf16x8 afr = *(const bf16x8*)&skv[(rt * 16 + ln15) * 200 + k0 + kg * 8];
        bf16x8 bfr = *(const bf16x8*)&wbv[((size_t)(ct * 16 + ln15)) * 192 + k0 + kg * 8];
        acc = __builtin_amdgcn_mfma_f32_16x16x32_bf16(afr, bfr, acc, 0, 0, 0);
      }
      #pragma unroll
      for (int r = 0; r < 4; ++r)
        vT[((size_t)b * 192 + ct * 16 + ln15) * 32 + rt * 16 + kg * 4 + r] = f2bf(acc[r]);
    }
  }
}

// ---------------------------------------------------------------------------
// attn v5: 16-row q tiles, grid 1024 (64 b x 16 qt), ~34.5KB LDS -> 4 blk/CU.
// q-LN results carried in registers ph0 -> ph5 (no qraw re-read/recompute).
// ---------------------------------------------------------------------------
__global__ __launch_bounds__(256, 4) void attn_kernel(
    const ushortT* __restrict__ qrawb, const float* __restrict__ ln_q_w,
    const float* __restrict__ ln_q_b, const float* __restrict__ kp,
    const ushortT* __restrict__ vT, const ushortT* __restrict__ wbq,
    const ushortT* __restrict__ wbo, const float* __restrict__ vw,
    const float* __restrict__ out_b, const float* __restrict__ ln_out_w,
    const float* __restrict__ ln_out_b, float* __restrict__ out) {
  __shared__ ushortT smem[17284];
  ushortT* sqln = smem;                   // [16][200] bf16
  float*   skp  = (float*)(smem + 3200);  // [32][132] f32
  float*   sqpF = (float*)(smem + 11648); // [16][132] f32
  float*   se   = (float*)(smem + 15872); // [16][36]  f32
  float*   swm  = (float*)(smem + 17024); // [128] f32
  float*   sS0  = (float*)(smem + 17280); // f32
  ushortT* sctx = smem;                   // [16][200] bf16 (over sqln)
  float*   sf   = (float*)(smem + 3200);  // [16][193] f32 (over skp)

  int b  = blockIdx.x >> 4;
  int t0 = (blockIdx.x & 15) * 16;
  int tid  = threadIdx.x;
  int wave = tid >> 6;
  int lane = tid & 63;
  int ln15 = lane & 15;
  int kg   = lane >> 4;

  {
    const float4* kp4 = (const float4*)(kp + (size_t)b * 4096);
    for (int j = tid; j < 1024; j += 256) {
      int row = j >> 5, c4 = j & 31;
      *(float4*)&skp[row * 132 + c4 * 4] = kp4[j];
    }
  }
  float qreg[4][3];
  {
    float w0 = ln_q_w[lane], w1 = ln_q_w[lane + 64], w2 = ln_q_w[lane + 128];
    float b0 = ln_q_b[lane], b1 = ln_q_b[lane + 64], b2 = ln_q_b[lane + 128];
    #pragma unroll
    for (int i = 0; i < 4; ++i) {
      int r = wave + i * 4;
      const ushortT* xr = qrawb + ((size_t)(b * 256 + t0 + r)) * 192;
      float v0 = bf2f(xr[lane]), v1 = bf2f(xr[lane + 64]), v2 = bf2f(xr[lane + 128]);
      float s = v0 + v1 + v2;
      float s2 = v0 * v0 + v1 * v1 + v2 * v2;
      #pragma unroll
      for (int off = 32; off; off >>= 1) { s += __shfl_xor(s, off); s2 += __shfl_xor(s2, off); }
      float mean = s * (1.f / 192.f);
      float var = s2 * (1.f / 192.f) - mean * mean;
      float inv = rsqrtf(var + 1e-5f);
      float q0 = (v0 - mean) * inv * w0 + b0;
      float q1 = (v1 - mean) * inv * w1 + b1;
      float q2 = (v2 - mean) * inv * w2 + b2;
      qreg[i][0] = q0; qreg[i][1] = q1; qreg[i][2] = q2;
      sqln[r * 200 + lane]       = f2bf(q0);
      sqln[r * 200 + lane + 64]  = f2bf(q1);
      sqln[r * 200 + lane + 128] = f2bf(q2);
    }
  }
  if (tid < 128) swm[tid] = -2.f * vw[tid];
  if (tid >= 128 && tid < 192) {
    int l = tid - 128;
    float s = vw[l] + vw[l + 64];
    #pragma unroll
    for (int off = 32; off; off >>= 1) s += __shfl_xor(s, off);
    if (l == 0) *sS0 = s;
  }
  __syncthreads();

  for (int ti = wave; ti < 8; ti += 4) {
    floatx4 acc = (floatx4)0.f;
    #pragma unroll
    for (int k0 = 0; k0 < 192; k0 += 32) {
      bf16x8 afr = *(const bf16x8*)&sqln[ln15 * 200 + k0 + kg * 8];
      bf16x8 bfr = *(const bf16x8*)&wbq[((size_t)(ti * 16 + ln15)) * 192 + k0 + kg * 8];
      acc = __builtin_amdgcn_mfma_f32_16x16x32_bf16(afr, bfr, acc, 0, 0, 0);
    }
    #pragma unroll
    for (int r = 0; r < 4; ++r)
      sqpF[(kg * 4 + r) * 132 + ti * 16 + ln15] = acc[r];
  }
  __syncthreads();

  {
    float S0v = *sS0;
    int qq = tid >> 4, kc = tid & 15;
    const float4* w4 = (const float4*)swm;
    const float4* q4 = (const float4*)&sqpF[qq * 132];
    const float4* ka = (const float4*)&skp[kc * 132];
    const float4* kb = (const float4*)&skp[(kc + 16) * 132];
    float acc0 = S0v, acc1 = S0v;
    #pragma unroll 8
    for (int d4 = 0; d4 < 32; ++d4) {
      float4 qv = q4[d4], k0v = ka[d4], k1v = kb[d4], wv = w4[d4];
      acc0 += wv.x * RCPF(EXP2F(qv.x + k0v.x) + 1.f);
      acc0 += wv.y * RCPF(EXP2F(qv.y + k0v.y) + 1.f);
      acc0 += wv.z * RCPF(EXP2F(qv.z + k0v.z) + 1.f);
      acc0 += wv.w * RCPF(EXP2F(qv.w + k0v.w) + 1.f);
      acc1 += wv.x * RCPF(EXP2F(qv.x + k1v.x) + 1.f);
      acc1 += wv.y * RCPF(EXP2F(qv.y + k1v.y) + 1.f);
      acc1 += wv.z * RCPF(EXP2F(qv.z + k1v.z) + 1.f);
      acc1 += wv.w * RCPF(EXP2F(qv.w + k1v.w) + 1.f);
    }
    float mx = fmaxf(acc0, acc1);
    #pragma unroll
    for (int off = 8; off; off >>= 1) mx = fmaxf(mx, __shfl_xor(mx, off));
    float e0 = __expf(acc0 - mx), e1 = __expf(acc1 - mx);
    float s = e0 + e1;
    #pragma unroll
    for (int off = 8; off; off >>= 1) s += __shfl_xor(s, off);
    float inv = 1.f / s;
    se[qq * 36 + kc]      = e0 * inv;
    se[qq * 36 + kc + 16] = e1 * inv;
  }
  __syncthreads();

  {
    float4 a0 = *(const float4*)&se[ln15 * 36 + kg * 8];
    float4 a1 = *(const float4*)&se[ln15 * 36 + kg * 8 + 4];
    ushort8v au;
    au[0] = f2bf(a0.x); au[1] = f2bf(a0.y); au[2] = f2bf(a0.z); au[3] = f2bf(a0.w);
    au[4] = f2bf(a1.x); au[5] = f2bf(a1.y); au[6] = f2bf(a1.z); au[7] = f2bf(a1.w);
    for (int ti = wave; ti < 12; ti += 4) {
      bf16x8 bfr = *(const bf16x8*)&vT[((size_t)(b * 192 + ti * 16 + ln15)) * 32 + kg * 8];
      floatx4 acc = __builtin_amdgcn_mfma_f32_16x16x32_bf16(
          __builtin_bit_cast(bf16x8, au), bfr, (floatx4)0.f, 0, 0, 0);
      #pragma unroll
      for (int r = 0; r < 4; ++r)
        sctx[(kg * 4 + r) * 200 + ti * 16 + ln15] = f2bf(acc[r]);
    }
  }
  __syncthreads();

  for (int ti = wave; ti < 12; ti += 4) {
    floatx4 acc = (floatx4)0.f;
    #pragma unroll
    for (int k0 = 0; k0 < 192; k0 += 32) {
      bf16x8 afr = *(const bf16x8*)&sctx[ln15 * 200 + k0 + kg * 8];
      bf16x8 bfr = *(const bf16x8*)&wbo[((size_t)(ti * 16 + ln15)) * 192 + k0 + kg * 8];
      acc = __builtin_amdgcn_mfma_f32_16x16x32_bf16(afr, bfr, acc, 0, 0, 0);
    }
    float bv = out_b[ti * 16 + ln15];
    #pragma unroll
    for (int r = 0; r < 4; ++r)
      sf[(kg * 4 + r) * 193 + ti * 16 + ln15] = acc[r] + bv;
  }
  __syncthreads();

  #pragma unroll
  for (int i = 0; i < 4; ++i) {
    int rr = wave + i * 4;
    float v0 = sf[rr * 193 + lane]       + qreg[i][0];
    float v1 = sf[rr * 193 + lane + 64]  + qreg[i][1];
    float v2 = sf[rr * 193 + lane + 128] + qreg[i][2];
    float t_s = v0 + v1 + v2;
    float t_s2 = v0 * v0 + v1 * v1 + v2 * v2;
    #pragma unroll
    for (int off = 32; off; off >>= 1) { t_s += __shfl_xor(t_s, off); t_s2 += __shfl_xor(t_s2, off); }
    float m2 = t_s * (1.f / 192.f);
    float var2 = t_s2 * (1.f / 192.f) - m2 * m2;
    float inv2 = rsqrtf(var2 + 1e-5f);
    sf[rr * 193 + lane]       = (v0 - m2) * inv2 * ln_out_w[lane]       + ln_out_b[lane];
    sf[rr * 193 + lane + 64]  = (v1 - m2) * inv2 * ln_out_w[lane + 64]  + ln_out_b[lane + 64];
    sf[rr * 193 + lane + 128] = (v2 - m2) * inv2 * ln_out_w[lane + 128] + ln_out_b[lane + 128];
  }
  __syncthreads();

  for (int j = tid; j < 768; j += 256) {
    int m = j >> 2, t4 = j & 3;
    float4 o4;
    o4.x = sf[(t4 * 4 + 0) * 193 + m];
    o4.y = sf[(t4 * 4 + 1) * 193 + m];
    o4.z = sf[(t4 * 4 + 2) * 193 + m];
    o4.w = sf[(t4 * 4 + 3) * 193 + m];
    *(float4*)&out[((size_t)(b * 192 + m)) * 256 + t0 + t4 * 4] = o4;
  }
}

// ---------------------------------------------------------------------------
extern "C" void kernel_launch(void* const* d_in, const int* in_sizes, int n_in,
                              void* d_out, int out_size, void* d_ws, size_t ws_size,
                              hipStream_t stream) {
  (void)in_sizes; (void)n_in; (void)out_size; (void)ws_size;
  const float* x_p     = (const float*)d_in[0];
  const float* y_g     = (const float*)d_in[1];
  const float* conv1_w = (const float*)d_in[2];
  const float* conv1_b = (const float*)d_in[3];
  const float* gamma1  = (const float*)d_in[4];
  const float* beta1   = (const float*)d_in[5];
  const float* conv2_w = (const float*)d_in[6];
  const float* conv2_b = (const float*)d_in[7];
  const float* gamma2  = (const float*)d_in[8];
  const float* beta2   = (const float*)d_in[9];
  const float* conv3_w = (const float*)d_in[10];
  const float* conv3_b = (const float*)d_in[11];
  const float* ln_q_w  = (const float*)d_in[12];
  const float* ln_q_b  = (const float*)d_in[13];
  const float* ln_kv_w = (const float*)d_in[14];
  const float* ln_kv_b = (const float*)d_in[15];
  const float* ln_out_w= (const float*)d_in[16];
  const float* ln_out_b= (const float*)d_in[17];
  const float* Wq      = (const float*)d_in[18];
  const float* Wk      = (const float*)d_in[19];
  const float* v_w     = (const float*)d_in[20];
  const float* Wv      = (const float*)d_in[21];
  const float* out_w   = (const float*)d_in[22];
  const float* out_b   = (const float*)d_in[23];
  float* out = (float*)d_out;
  float* ws  = (float*)d_ws;

  ushortT* x2bf  = (ushortT*)(ws + OFF_X2BF);
  ushortT* x3bf  = (ushortT*)(ws + OFF_X3BF);
  ushortT* qrawb = (ushortT*)(ws + OFF_QRAW);
  ushortT* wbq   = (ushortT*)(ws + OFF_WBQ);
  ushortT* wbk   = (ushortT*)(ws + OFF_WBK);
  ushortT* wbv   = (ushortT*)(ws + OFF_WBV);
  ushortT* wbo   = (ushortT*)(ws + OFF_WBO);
  ushortT* wt2   = (ushortT*)(ws + OFF_WT2);
  ushortT* wt3   = (ushortT*)(ws + OFF_WT3);
  ushortT* wc1   = (ushortT*)(ws + OFF_WC1);
  ushortT* gb1   = (ushortT*)(ws + OFF_GB1);
  ushortT* gb2   = (ushortT*)(ws + OFF_GB2);
  float*   kp    = (float*)(ws + OFF_KP);
  ushortT* vTb   = (ushortT*)(ws + OFF_VT);

  prep_kernel<<<3152, 256, 0, stream>>>(conv2_w, wt2, conv3_w, wt3, conv1_w, wc1,
                                        Wq, wbq, Wk, wbk, Wv, wbv, out_w, wbo,
                                        gamma1, gb1, gamma2, gb2);
  kv_prep_kernel<<<64, 256, 0, stream>>>(y_g, ln_kv_w, ln_kv_b, wbk, wbv,
                                         kp, vTb);
  conv1_gdn_kernel<<<512, 256, 0, stream>>>(x_p, wc1, conv1_b, gb1, beta1, x2bf);
  conv2_gdn_kernel<<<256, 512, 0, stream>>>(x2bf, wt2, conv2_b, gb2, beta2, x3bf);
  conv3_mfma_kernel<<<768, 256, 0, stream>>>(x3bf, wt3, conv3_b, qrawb);
  attn_kernel<<<1024, 256, 0, stream>>>(qrawb, ln_q_w, ln_q_b, kp, vTb,
                                        wbq, wbo, v_w, out_b, ln_out_w,
                                        ln_out_b, out);
}

// Round 5
// 217.669 us; speedup vs baseline: 1.2550x; 1.2550x over previous
//
#include <hip/hip_runtime.h>
#include <cstddef>
#include <cstdint>

// ---------------------------------------------------------------------------
// Pipeline (5 launches):
//   prep (weight repack)
//   -> conv1+GDN1 fused + kv_prep merged (block-range dispatch, grid 576)
//   -> conv2+GDN2 fused (4-row x 512-thread blocks, grid 256, reg prefetch)
//   -> conv3 3x3 (MFMA, reg prefetch) -> attn v5 (q-LN carried in regs).
// ---------------------------------------------------------------------------

typedef __bf16 bf16x8 __attribute__((ext_vector_type(8)));
typedef float floatx4 __attribute__((ext_vector_type(4)));
typedef unsigned short ushortT;
typedef unsigned short ushort8v __attribute__((ext_vector_type(8)));

#if __has_builtin(__builtin_amdgcn_exp2f)
#define EXP2F(x) __builtin_amdgcn_exp2f(x)
#else
#define EXP2F(x) exp2f(x)
#endif
#if __has_builtin(__builtin_amdgcn_rcpf)
#define RCPF(x) __builtin_amdgcn_rcpf(x)
#else
#define RCPF(x) (1.f / (x))
#endif

__device__ __forceinline__ ushortT f2bf(float f) {
  unsigned u = __builtin_bit_cast(unsigned, f);
  unsigned r = (u + 0x7FFFu + ((u >> 16) & 1u)) >> 16;
  return (ushortT)r;
}
__device__ __forceinline__ float bf2f(ushortT u) {
  return __builtin_bit_cast(float, ((unsigned)u) << 16);
}

// ---- workspace layout (float-slot offsets) ----
static constexpr size_t OFF_X2BF = 4194304;    // gdn1 out bf16 [b][4][256][128]
static constexpr size_t OFF_X3BF = 9437184;    // gdn2 out bf16 (64,256,128)
static constexpr size_t OFF_QRAW = 10485760;   // conv3 out bf16 (64,256,192)
static constexpr size_t OFF_WBQ  = 21299200;   // bf16 128x192 (scaled by c)
static constexpr size_t OFF_WBK  = 21311488;   // bf16 128x192 (scaled by c)
static constexpr size_t OFF_WBV  = 21323776;   // bf16 192x192
static constexpr size_t OFF_WBO  = 21342208;   // bf16 192x192
static constexpr size_t OFF_WT2  = 26079232;   // bf16 conv2 slabs [200][2048]
static constexpr size_t OFF_WT3  = 26284032;   // bf16 conv3 slabs [108][2048]
static constexpr size_t OFF_WC1  = 26394624;   // bf16 conv1 slabs [5][128][32]
static constexpr size_t OFF_GB1  = 26406912;   // bf16 gamma1 128x128
static constexpr size_t OFF_GB2  = 26415104;   // bf16 gamma2 128x128
// kv_prep outputs live in the (unused) low region:
static constexpr size_t OFF_KP   = 0;          // f32  [64][32][128]
static constexpr size_t OFF_VT   = 262144;     // bf16 [64][192][32]

// 5x5 s2 p2 polyphase tap tables (tap id = kh*5+kw); HW-verified via conv2.
__device__ __constant__ int d_TWI2[4][9] = {{ 0, 2, 4,10,12,14,20,22,24},
                                            { 1, 3,11,13,21,23, 0, 0, 0},
                                            { 5, 7, 9,15,17,19, 0, 0, 0},
                                            { 6, 8,16,18, 0, 0, 0, 0, 0}};
__device__ __constant__ int d_NT2[4] = {9, 6, 6, 4};

// ---------------------------------------------------------------------------
// fused prep: all weight repacks/casts in one launch, block-range dispatch.
// ---------------------------------------------------------------------------
__device__ void dev_convw3(const float* w, ushortT* wt, int mode, int total,
                           int idx) {
  if (idx >= total) return;
  int j    = idx & 7;
  int om   = (idx >> 3) & 63;
  int kg   = (idx >> 9) & 3;
  int slab = idx >> 11;
  int mt, s, tap, T;
  if (mode == 0) {
    int ph;
    if (slab < 72) ph = 0; else if (slab < 120) ph = 1;
    else if (slab < 168) ph = 2; else ph = 3;
    const int st[4] = {0, 72, 120, 168};
    const int ns[4] = {36, 24, 24, 16};
    int rel = slab - st[ph];
    mt = rel / ns[ph]; s = rel % ns[ph];
    tap = d_TWI2[ph][s >> 2]; T = 25;
  } else {
    mt = slab / 36; s = slab % 36; tap = s >> 2; T = 9;
  }
  int cc = s & 3;
  int c  = cc * 32 + kg * 8 + j;
  int oc = mt * 64 + om;
  wt[idx] = f2bf(w[(size_t)(oc * 128 + c) * T + tap]);
}

__device__ void dev_convw1(const float* w, ushortT* wt, int idx) {
  if (idx >= 20480) return;
  int k    = idx & 31;
  int oc   = (idx >> 5) & 127;
  int slab = idx >> 12;
  int ph, i;
  if (slab < 2) { ph = 0; i = slab; } else { ph = slab - 1; i = 0; }
  int kg = k >> 3, jj = k & 7;
  int tidx = i * 8 + jj;
  float val = 0.f;
  if (kg < 3 && tidx < d_NT2[ph]) {
    int tap = d_TWI2[ph][tidx];
    val = w[(size_t)(oc * 3 + kg) * 25 + tap];
  }
  wt[idx] = f2bf(val);
}

__device__ void dev_wcast(const float* w, ushortT* wb, int total, float scale,
                          int idx) {
  if (idx < total) wb[idx] = f2bf(w[idx] * scale);
}

__global__ __launch_bounds__(256) void prep_kernel(
    const float* __restrict__ conv2_w, ushortT* __restrict__ wt2,
    const float* __restrict__ conv3_w, ushortT* __restrict__ wt3,
    const float* __restrict__ conv1_w, ushortT* __restrict__ wc1,
    const float* __restrict__ Wq, ushortT* __restrict__ wbq,
    const float* __restrict__ Wk, ushortT* __restrict__ wbk,
    const float* __restrict__ Wv, ushortT* __restrict__ wbv,
    const float* __restrict__ out_w, ushortT* __restrict__ wbo,
    const float* __restrict__ gamma1, ushortT* __restrict__ gb1,
    const float* __restrict__ gamma2, ushortT* __restrict__ gb2) {
  constexpr float C2LE = 2.88539008177792681f;   // 2*log2(e)
  int blk = blockIdx.x, tid = threadIdx.x;
  if (blk < 1600)      dev_convw3(conv2_w, wt2, 0, 409600, blk * 256 + tid);
  else if (blk < 2464) dev_convw3(conv3_w, wt3, 1, 221184, (blk - 1600) * 256 + tid);
  else if (blk < 2544) dev_convw1(conv1_w, wc1, (blk - 2464) * 256 + tid);
  else if (blk < 2640) dev_wcast(Wq, wbq, 24576, C2LE, (blk - 2544) * 256 + tid);
  else if (blk < 2736) dev_wcast(Wk, wbk, 24576, C2LE, (blk - 2640) * 256 + tid);
  else if (blk < 2880) dev_wcast(Wv, wbv, 36864, 1.f, (blk - 2736) * 256 + tid);
  else if (blk < 3024) dev_wcast(out_w, wbo, 36864, 1.f, (blk - 2880) * 256 + tid);
  else if (blk < 3088) dev_wcast(gamma1, gb1, 16384, 1.f, (blk - 3024) * 256 + tid);
  else                 dev_wcast(gamma2, gb2, 16384, 1.f, (blk - 3088) * 256 + tid);
}

// ---------------------------------------------------------------------------
// conv1+GDN1 fused (blocks 0..511) + kv_prep (blocks 512..575), merged via
// block-range dispatch. Shared static LDS 56832B -> 2 blocks/CU.
// ---------------------------------------------------------------------------
__global__ __launch_bounds__(256, 2) void conv1_kv_kernel(
    const float* __restrict__ x, const ushortT* __restrict__ wc1,
    const float* __restrict__ bias, const ushortT* __restrict__ gb1,
    const float* __restrict__ beta1, ushortT* __restrict__ outb,
    const float* __restrict__ yg, const float* __restrict__ ln_kv_w,
    const float* __restrict__ ln_kv_b, const ushortT* __restrict__ wbk,
    const ushortT* __restrict__ wbv, float* __restrict__ kp,
    ushortT* __restrict__ vT) {
  __shared__ ushortT smem[28416];
  int tid  = threadIdx.x;
  int wave = tid >> 6;
  int lane = tid & 63;
  int ln15 = lane & 15;
  int kg   = lane >> 4;

  if (blockIdx.x >= 512) {
    // ---------------- kv_prep path ----------------
    int b = blockIdx.x - 512;
    float*   skvRaw = (float*)smem;        // [32][194] f32 (24832B)
    ushortT* skv    = smem + 12416;        // [32][200] bf16 (12800 ush)

    const float4* yg4 = (const float4*)(yg + (size_t)b * 6144);
    for (int j = tid; j < 1536; j += 256) {
      float4 v = yg4[j];
      int c = j >> 3;
      int t4 = (j & 7) * 4;
      skvRaw[(t4 + 0) * 194 + c] = v.x;
      skvRaw[(t4 + 1) * 194 + c] = v.y;
      skvRaw[(t4 + 2) * 194 + c] = v.z;
      skvRaw[(t4 + 3) * 194 + c] = v.w;
    }
    __syncthreads();
    for (int r = wave; r < 32; r += 4) {
      const float* src = skvRaw + r * 194;
      float v0 = src[lane], v1 = src[lane + 64], v2 = src[lane + 128];
      float s = v0 + v1 + v2;
      float s2 = v0 * v0 + v1 * v1 + v2 * v2;
      #pragma unroll
      for (int off = 32; off; off >>= 1) { s += __shfl_xor(s, off); s2 += __shfl_xor(s2, off); }
      float mean = s * (1.f / 192.f);
      float var = s2 * (1.f / 192.f) - mean * mean;
      float inv = rsqrtf(var + 1e-5f);
      skv[r * 200 + lane]       = f2bf((v0 - mean) * inv * ln_kv_w[lane]       + ln_kv_b[lane]);
      skv[r * 200 + lane + 64]  = f2bf((v1 - mean) * inv * ln_kv_w[lane + 64]  + ln_kv_b[lane + 64]);
      skv[r * 200 + lane + 128] = f2bf((v2 - mean) * inv * ln_kv_w[lane + 128] + ln_kv_b[lane + 128]);
    }
    __syncthreads();
    for (int ti = wave; ti < 40; ti += 4) {
      floatx4 acc = (floatx4)0.f;
      if (ti < 16) {
        int rt = ti >> 3, ct = ti & 7;
        #pragma unroll
        for (int k0 = 0; k0 < 192; k0 += 32) {
          bf16x8 afr = *(const bf16x8*)&skv[(rt * 16 + ln15) * 200 + k0 + kg * 8];
          bf16x8 bfr = *(const bf16x8*)&wbk[((size_t)(ct * 16 + ln15)) * 192 + k0 + kg * 8];
          acc = __builtin_amdgcn_mfma_f32_16x16x32_bf16(afr, bfr, acc, 0, 0, 0);
        }
        #pragma unroll
        for (int r = 0; r < 4; ++r)
          kp[((size_t)b * 32 + rt * 16 + kg * 4 + r) * 128 + ct * 16 + ln15] = acc[r];
      } else {
        int t2 = ti - 16;
        int rt = t2 / 12, ct = t2 % 12;
        #pragma unroll
        for (int k0 = 0; k0 < 192; k0 += 32) {
          bf16x8 afr = *(const bf16x8*)&skv[(rt * 16 + ln15) * 200 + k0 + kg * 8];
          bf16x8 bfr = *(const bf16x8*)&wbv[((size_t)(ct * 16 + ln15)) * 192 + k0 + kg * 8];
          acc = __builtin_amdgcn_mfma_f32_16x16x32_bf16(afr, bfr, acc, 0, 0, 0);
        }
        #pragma unroll
        for (int r = 0; r < 4; ++r)
          vT[((size_t)b * 192 + ct * 16 + ln15) * 32 + rt * 16 + kg * 4 + r] = f2bf(acc[r]);
      }
    }
    return;
  }

  // ---------------- conv1+GDN1 path ----------------
  int b  = blockIdx.x >> 3;
  int yg_ = blockIdx.x & 7;
  int y0 = yg_ * 4;

  ushortT* simg = smem;
  ushortT* sA   = smem + 2816;

  for (int j = tid; j < 1408; j += 256) ((unsigned*)simg)[j] = 0u;
  __syncthreads();

  int ihBase = 2 * y0 - 2;
  const float* xb = x + (size_t)b * 3 * 4096;
  for (int j = tid; j < 576; j += 256) {
    int q = j & 15;
    int rr = j >> 4;
    int c = rr / 12, ihl = rr % 12;
    int ih = ihBase + ihl;
    if (ih >= 0 && ih < 64) {
      float4 v = *(const float4*)&xb[c * 4096 + ih * 64 + q * 4];
      int pr = ih & 1, u = ih >> 1;
      int lr = u - y0 + 1;
      int base0 = ((pr * 2 + 0) * 3 + c) * 216 + lr * 36;
      int base1 = ((pr * 2 + 1) * 3 + c) * 216 + lr * 36;
      simg[base0 + 2 * q + 1] = f2bf(v.x);
      simg[base1 + 2 * q + 1] = f2bf(v.y);
      simg[base0 + 2 * q + 2] = f2bf(v.z);
      simg[base1 + 2 * q + 2] = f2bf(v.w);
    }
  }
  for (int j = tid; j < 2560; j += 256) {
    int chunk = j & 3, row = j >> 2;
    uint4 v = *(const uint4*)&wc1[row * 32 + chunk * 8];
    *(uint4*)&sA[row * 40 + chunk * 8] = v;
  }
  __syncthreads();

  constexpr int TDR[4][9] = {{-1,-1,-1, 0, 0, 0, 1, 1, 1},
                             {-1,-1, 0, 0, 1, 1, 0, 0, 0},
                             {-1,-1,-1, 0, 0, 0, 0, 0, 0},
                             {-1,-1, 0, 0, 0, 0, 0, 0, 0}};
  constexpr int TDC[4][9] = {{-1, 0, 1,-1, 0, 1,-1, 0, 1},
                             {-1, 0,-1, 0,-1, 0, 0, 0, 0},
                             {-1, 0, 1,-1, 0, 1, 0, 0, 0},
                             {-1, 0,-1, 0, 0, 0, 0, 0, 0}};
  constexpr int NT[4]  = {9, 6, 6, 4};
  constexpr int NM[4]  = {2, 1, 1, 1};
  constexpr int SB[4]  = {0, 2, 3, 4};

  ushort8v Bf[2][5];
  #pragma unroll
  for (int ntl = 0; ntl < 2; ++ntl) {
    int ntg = wave * 2 + ntl;
    int yloc = ntg >> 1;
    int xx = (ntg & 1) * 16 + ln15;
    int lbase = (yloc + 1) * 36 + xx + 1 + kg * 216;
    #pragma unroll
    for (int ph = 0; ph < 4; ++ph) {
      int pbase = ph * 648 + lbase;
      #pragma unroll
      for (int i = 0; i < 2; ++i) {
        if (i < NM[ph]) {
          ushort8v bv;
          #pragma unroll
          for (int j = 0; j < 8; ++j) {
            int tidx = i * 8 + j;
            if (tidx >= NT[ph]) tidx = 0;
            int off = TDR[ph][tidx] * 36 + TDC[ph][tidx];
            bv[j] = simg[pbase + off];
          }
          Bf[ntl][SB[ph] + i] = bv;
        }
      }
    }
  }

  ushort4 xq[8][2];
  #pragma unroll
  for (int m = 0; m < 8; ++m) {
    bf16x8 Af[5];
    #pragma unroll
    for (int s = 0; s < 5; ++s)
      Af[s] = *(const bf16x8*)&sA[(s * 128 + m * 16 + ln15) * 40 + kg * 8];
    int oc0 = m * 16 + kg * 4;
    float4 bv = *(const float4*)&bias[oc0];
    #pragma unroll
    for (int ntl = 0; ntl < 2; ++ntl) {
      floatx4 acc = (floatx4)0.f;
      #pragma unroll
      for (int s = 0; s < 5; ++s)
        acc = __builtin_amdgcn_mfma_f32_16x16x32_bf16(
            Af[s], __builtin_bit_cast(bf16x8, Bf[ntl][s]), acc, 0, 0, 0);
      ushort4 o4 = {f2bf(acc[0] + bv.x), f2bf(acc[1] + bv.y),
                    f2bf(acc[2] + bv.z), f2bf(acc[3] + bv.w)};
      xq[m][ntl] = o4;
    }
  }
  __syncthreads();   // conv LDS reads done -> safe to overwrite with gamma

  for (int j = tid; j < 2048; j += 256) {
    int row = j >> 4, ch = j & 15;
    *(uint4*)&smem[row * 136 + ch * 8] = *(const uint4*)&gb1[row * 128 + ch * 8];
  }
  __syncthreads();

  const int sxbase = 17408 + wave * 2176;   // per-wave x^2 slab [16][136]
  #pragma unroll
  for (int q = 0; q < 2; ++q) {
    #pragma unroll
    for (int m = 0; m < 8; ++m) {
      ushort4 xv = xq[m][q];
      float f0 = bf2f(xv.x), f1 = bf2f(xv.y), f2 = bf2f(xv.z), f3 = bf2f(xv.w);
      ushort4 s4 = {f2bf(f0 * f0), f2bf(f1 * f1), f2bf(f2 * f2), f2bf(f3 * f3)};
      *(ushort4*)&smem[sxbase + ln15 * 136 + m * 16 + kg * 4] = s4;
    }
    int ntg = wave * 2 + q;
    int y = y0 + (ntg >> 1);
    int xx = (ntg & 1) * 16 + ln15;
    int ph = ((y & 1) << 1) | (xx & 1);
    size_t dstbase = (((size_t)b * 4 + ph) * 256 + (y >> 1) * 16 + (xx >> 1)) * 128;
    #pragma unroll
    for (int dt = 0; dt < 8; ++dt) {
      floatx4 acc = (floatx4)0.f;
      #pragma unroll
      for (int k0 = 0; k0 < 4; ++k0) {
        bf16x8 ga = *(const bf16x8*)&smem[(dt * 16 + ln15) * 136 + k0 * 32 + kg * 8];
        bf16x8 xbv = *(const bf16x8*)&smem[sxbase + ln15 * 136 + k0 * 32 + kg * 8];
        acc = __builtin_amdgcn_mfma_f32_16x16x32_bf16(ga, xbv, acc, 0, 0, 0);
      }
      int d0 = dt * 16 + kg * 4;
      float4 bt = *(const float4*)&beta1[d0];
      ushort4 xv = xq[dt][q];
      ushort4 o4;
      o4.x = f2bf(bf2f(xv.x) * rsqrtf(acc[0] + bt.x));
      o4.y = f2bf(bf2f(xv.y) * rsqrtf(acc[1] + bt.y));
      o4.z = f2bf(bf2f(xv.z) * rsqrtf(acc[2] + bt.z));
      o4.w = f2bf(bf2f(xv.w) * rsqrtf(acc[3] + bt.w));
      *(ushort4*)&outb[dstbase + d0] = o4;
    }
  }
}

// ---------------------------------------------------------------------------
// conv2+GDN2 fused (R3 structure): 4 rows x 16 px x 128 oc per block, 512
// threads, grid 256 (1 blk/CU, 8 waves). wave = (wrow 0..3, whalf 0..1).
// Weights direct from L2 with register prefetch. gamma2 read from global.
// ---------------------------------------------------------------------------
__global__ __launch_bounds__(512, 2) void conv2_gdn_kernel(
    const ushortT* __restrict__ X, const ushortT* __restrict__ Wt,
    const float* __restrict__ bias, const ushortT* __restrict__ gb2,
    const float* __restrict__ beta2, ushortT* __restrict__ outb) {
  int b  = blockIdx.x >> 2;
  int rs = blockIdx.x & 3;
  int r0 = rs * 4;

  int tid  = threadIdx.x;
  int wave = tid >> 6;
  int lane = tid & 63;
  int ln15 = lane & 15;
  int kg   = lane >> 4;
  int wrow  = wave & 3;
  int whalf = wave >> 2;

  // simg [0,14688) [6 rows][18][136]; sX2 [14688,23392) [64 px][136]
  __shared__ ushortT smem[23392];
  ushortT* simg = smem;
  ushortT* sX2  = smem + 14688;

  floatx4 acc[4];
  #pragma unroll
  for (int m = 0; m < 4; ++m) acc[m] = (floatx4)0.f;

  constexpr int NS2[4]      = {36, 24, 24, 16};
  constexpr int PHSTART2[4] = {0, 72, 120, 168};
  constexpr int TDR_2[4][9] = {{-1,-1,-1, 0, 0, 0, 1, 1, 1},
                               {-1,-1, 0, 0, 1, 1, 0, 0, 0},
                               {-1,-1,-1, 0, 0, 0, 0, 0, 0},
                               {-1,-1, 0, 0, 0, 0, 0, 0, 0}};
  constexpr int TDC_2[4][9] = {{-1, 0, 1,-1, 0, 1,-1, 0, 1},
                               {-1, 0,-1, 0,-1, 0, 0, 0, 0},
                               {-1, 0, 1,-1, 0, 1, 0, 0, 0},
                               {-1, 0,-1, 0, 0, 0, 0, 0, 0}};

  const int aoff = kg * 512 + ln15 * 8;
  uint4 apf[8][4];

  #pragma unroll
  for (int ph = 0; ph < 4; ++ph) {
    const int NS = NS2[ph];
    const ushortT* wp0 = Wt + (size_t)(PHSTART2[ph] + whalf * NS) * 2048 + aoff;

    __syncthreads();
    const ushortT* Xb = X + (((size_t)b * 4 + ph) * 256) * 128;
    for (int idx = tid; idx < 1728; idx += 512) {
      int chunk = idx & 15;
      int pix = idx >> 4;
      int row = pix / 18, colm = pix - row * 18;
      int i = r0 - 1 + row, j = colm - 1;
      uint4 v = {0u, 0u, 0u, 0u};
      if (i >= 0 && i < 16 && j >= 0 && j < 16)
        v = *(const uint4*)(Xb + ((size_t)(i * 16 + j)) * 128 + chunk * 8);
      *(uint4*)&simg[(row * 18 + colm) * 136 + chunk * 8] = v;
    }
    #pragma unroll
    for (int jj = 0; jj < 8; ++jj) {
      #pragma unroll
      for (int m = 0; m < 4; ++m)
        apf[jj][m] = *(const uint4*)(wp0 + (size_t)jj * 2048 + m * 128);
    }
    __syncthreads();

    #pragma unroll
    for (int s0 = 0; s0 < NS; s0 += 8) {
      #pragma unroll
      for (int jj = 0; jj < 8; ++jj) {
        int s = s0 + jj;
        if (s < NS) {
          bf16x8 acur[4];
          #pragma unroll
          for (int m = 0; m < 4; ++m) acur[m] = __builtin_bit_cast(bf16x8, apf[jj][m]);
          int sp = s + 8;
          if (sp < NS) {
            #pragma unroll
            for (int m = 0; m < 4; ++m)
              apf[jj][m] = *(const uint4*)(wp0 + (size_t)sp * 2048 + m * 128);
          }
          int t  = s >> 2;
          int c0 = (s & 3) * 32;
          int dr = TDR_2[ph][t];
          int dc = TDC_2[ph][t];
          int lrow = wrow + dr + 1;
          int lcol = ln15 + dc + 1;
          bf16x8 bfr = *(const bf16x8*)&simg[(lrow * 18 + lcol) * 136 + c0 + kg * 8];
          #pragma unroll
          for (int m = 0; m < 4; ++m)
            acc[m] = __builtin_amdgcn_mfma_f32_16x16x32_bf16(acur[m], bfr, acc[m], 0, 0, 0);
        }
      }
    }
  }

  // ---- GDN2 in-block ----
  ushort4 xq2[4];
  #pragma unroll
  for (int m = 0; m < 4; ++m) {
    int mg = whalf * 64 + m * 16 + kg * 4;
    float4 bv = *(const float4*)&bias[mg];
    ushort4 o4 = {f2bf(acc[m][0] + bv.x), f2bf(acc[m][1] + bv.y),
                  f2bf(acc[m][2] + bv.z), f2bf(acc[m][3] + bv.w)};
    xq2[m] = o4;
    float f0 = bf2f(o4.x), f1 = bf2f(o4.y), f2 = bf2f(o4.z), f3 = bf2f(o4.w);
    ushort4 s4 = {f2bf(f0 * f0), f2bf(f1 * f1), f2bf(f2 * f2), f2bf(f3 * f3)};
    *(ushort4*)&sX2[(wrow * 16 + ln15) * 136 + mg] = s4;
  }
  __syncthreads();

  int p = (r0 + wrow) * 16 + ln15;
  size_t obase = ((size_t)b * 256 + p) * 128;
  #pragma unroll
  for (int dti = 0; dti < 4; ++dti) {
    int dt = whalf * 4 + dti;
    floatx4 nacc = (floatx4)0.f;
    #pragma unroll
    for (int k0 = 0; k0 < 4; ++k0) {
      bf16x8 ga = *(const bf16x8*)&gb2[(size_t)(dt * 16 + ln15) * 128 + k0 * 32 + kg * 8];
      bf16x8 xbv = *(const bf16x8*)&sX2[(wrow * 16 + ln15) * 136 + k0 * 32 + kg * 8];
      nacc = __builtin_amdgcn_mfma_f32_16x16x32_bf16(ga, xbv, nacc, 0, 0, 0);
    }
    int d0 = dt * 16 + kg * 4;
    float4 bt = *(const float4*)&beta2[d0];
    ushort4 xv = xq2[dti];
    ushort4 o4;
    o4.x = f2bf(bf2f(xv.x) * rsqrtf(nacc[0] + bt.x));
    o4.y = f2bf(bf2f(xv.y) * rsqrtf(nacc[1] + bt.y));
    o4.z = f2bf(bf2f(xv.z) * rsqrtf(nacc[2] + bt.z));
    o4.w = f2bf(bf2f(xv.w) * rsqrtf(nacc[3] + bt.w));
    *(ushort4*)&outb[obase + d0] = o4;
  }
}

// ---------------------------------------------------------------------------
// conv3 MFMA implicit GEMM (3x3 s1, R3 structure); 4-row split, 2 blocks/CU.
// ---------------------------------------------------------------------------
__global__ __launch_bounds__(256, 2) void conv3_mfma_kernel(
    const ushortT* __restrict__ X,
    const ushortT* __restrict__ Wt,
    const float* __restrict__ bias,
    ushortT* __restrict__ outb) {
  constexpr int OC  = 192;
  constexpr int NMT = 3;

  int b   = blockIdx.x / (NMT * 4);
  int rem = blockIdx.x % (NMT * 4);
  int mt  = rem >> 2;
  int rs  = rem & 3;
  int r0  = rs * 4;

  int wave = threadIdx.x >> 6;
  int lane = threadIdx.x & 63;
  int ln15 = lane & 15;
  int kg   = lane >> 4;

  __shared__ ushortT simg[6 * 18 * 136];

  floatx4 acc[4];
  #pragma unroll
  for (int m = 0; m < 4; ++m) acc[m] = (floatx4)0.f;

  constexpr int TDR_3[9] = {-1,-1,-1, 0, 0, 0, 1, 1, 1};
  constexpr int TDC_3[9] = {-1, 0, 1,-1, 0, 1,-1, 0, 1};

  const int aoff = kg * 512 + ln15 * 8;
  uint4 apf[8][4];

  {
    const int NS = 36;
    const ushortT* wp0 = Wt + (size_t)(mt * 36) * 2048 + aoff;

    const ushortT* Xb = X + ((size_t)b * 256) * 128;
    for (int idx = threadIdx.x; idx < 1728; idx += 256) {
      int chunk = idx & 15;
      int pix = idx >> 4;
      int row = pix / 18, colm = pix - row * 18;
      int i = r0 - 1 + row, j = colm - 1;
      uint4 v = {0u, 0u, 0u, 0u};
      if (i >= 0 && i < 16 && j >= 0 && j < 16)
        v = *(const uint4*)(Xb + ((size_t)(i * 16 + j)) * 128 + chunk * 8);
      *(uint4*)&simg[(row * 18 + colm) * 136 + chunk * 8] = v;
    }
    #pragma unroll
    for (int jj = 0; jj < 8; ++jj) {
      #pragma unroll
      for (int m = 0; m < 4; ++m)
        apf[jj][m] = *(const uint4*)(wp0 + (size_t)jj * 2048 + m * 128);
    }
    __syncthreads();

    #pragma unroll
    for (int s0 = 0; s0 < 36; s0 += 8) {
      #pragma unroll
      for (int jj = 0; jj < 8; ++jj) {
        int s = s0 + jj;
        if (s < 36) {
          bf16x8 acur[4];
          #pragma unroll
          for (int m = 0; m < 4; ++m) acur[m] = __builtin_bit_cast(bf16x8, apf[jj][m]);
          int sp = s + 8;
          if (sp < 36) {
            #pragma unroll
            for (int m = 0; m < 4; ++m)
              apf[jj][m] = *(const uint4*)(wp0 + (size_t)sp * 2048 + m * 128);
          }
          int t  = s >> 2;
          int c0 = (s & 3) * 32;
          int lrow = wave + TDR_3[t] + 1;
          int lcol = ln15 + TDC_3[t] + 1;
          bf16x8 bfr = *(const bf16x8*)&simg[(lrow * 18 + lcol) * 136 + c0 + kg * 8];
          #pragma unroll
          for (int m = 0; m < 4; ++m)
            acc[m] = __builtin_amdgcn_mfma_f32_16x16x32_bf16(acur[m], bfr, acc[m], 0, 0, 0);
        }
      }
    }
  }

  #pragma unroll
  for (int m = 0; m < 4; ++m) {
    int mg = mt * 64 + m * 16 + kg * 4;
    float4 bv = *(const float4*)&bias[mg];
    int r = r0 + wave;
    int p = r * 16 + ln15;
    ushort4 o4 = {f2bf(acc[m][0] + bv.x), f2bf(acc[m][1] + bv.y),
                  f2bf(acc[m][2] + bv.z), f2bf(acc[m][3] + bv.w)};
    *(ushort4*)&outb[((size_t)b * 256 + p) * OC + mg] = o4;
  }
}

// ---------------------------------------------------------------------------
// attn v5: 16-row q tiles, grid 1024 (64 b x 16 qt), ~34.5KB LDS -> 4 blk/CU.
// q-LN results carried in registers ph0 -> ph5 (no qraw re-read/recompute).
// ---------------------------------------------------------------------------
__global__ __launch_bounds__(256, 4) void attn_kernel(
    const ushortT* __restrict__ qrawb, const float* __restrict__ ln_q_w,
    const float* __restrict__ ln_q_b, const float* __restrict__ kp,
    const ushortT* __restrict__ vT, const ushortT* __restrict__ wbq,
    const ushortT* __restrict__ wbo, const float* __restrict__ vw,
    const float* __restrict__ out_b, const float* __restrict__ ln_out_w,
    const float* __restrict__ ln_out_b, float* __restrict__ out) {
  __shared__ ushortT smem[17284];
  ushortT* sqln = smem;                   // [16][200] bf16
  float*   skp  = (float*)(smem + 3200);  // [32][132] f32
  float*   sqpF = (float*)(smem + 11648); // [16][132] f32
  float*   se   = (float*)(smem + 15872); // [16][36]  f32
  float*   swm  = (float*)(smem + 17024); // [128] f32
  float*   sS0  = (float*)(smem + 17280); // f32
  ushortT* sctx = smem;                   // [16][200] bf16 (over sqln)
  float*   sf   = (float*)(smem + 3200);  // [16][193] f32 (over skp)

  int b  = blockIdx.x >> 4;
  int t0 = (blockIdx.x & 15) * 16;
  int tid  = threadIdx.x;
  int wave = tid >> 6;
  int lane = tid & 63;
  int ln15 = lane & 15;
  int kg   = lane >> 4;

  {
    const float4* kp4 = (const float4*)(kp + (size_t)b * 4096);
    for (int j = tid; j < 1024; j += 256) {
      int row = j >> 5, c4 = j & 31;
      *(float4*)&skp[row * 132 + c4 * 4] = kp4[j];
    }
  }
  float qreg[4][3];
  {
    float w0 = ln_q_w[lane], w1 = ln_q_w[lane + 64], w2 = ln_q_w[lane + 128];
    float b0 = ln_q_b[lane], b1 = ln_q_b[lane + 64], b2 = ln_q_b[lane + 128];
    #pragma unroll
    for (int i = 0; i < 4; ++i) {
      int r = wave + i * 4;
      const ushortT* xr = qrawb + ((size_t)(b * 256 + t0 + r)) * 192;
      float v0 = bf2f(xr[lane]), v1 = bf2f(xr[lane + 64]), v2 = bf2f(xr[lane + 128]);
      float s = v0 + v1 + v2;
      float s2 = v0 * v0 + v1 * v1 + v2 * v2;
      #pragma unroll
      for (int off = 32; off; off >>= 1) { s += __shfl_xor(s, off); s2 += __shfl_xor(s2, off); }
      float mean = s * (1.f / 192.f);
      float var = s2 * (1.f / 192.f) - mean * mean;
      float inv = rsqrtf(var + 1e-5f);
      float q0 = (v0 - mean) * inv * w0 + b0;
      float q1 = (v1 - mean) * inv * w1 + b1;
      float q2 = (v2 - mean) * inv * w2 + b2;
      qreg[i][0] = q0; qreg[i][1] = q1; qreg[i][2] = q2;
      sqln[r * 200 + lane]       = f2bf(q0);
      sqln[r * 200 + lane + 64]  = f2bf(q1);
      sqln[r * 200 + lane + 128] = f2bf(q2);
    }
  }
  if (tid < 128) swm[tid] = -2.f * vw[tid];
  if (tid >= 128 && tid < 192) {
    int l = tid - 128;
    float s = vw[l] + vw[l + 64];
    #pragma unroll
    for (int off = 32; off; off >>= 1) s += __shfl_xor(s, off);
    if (l == 0) *sS0 = s;
  }
  __syncthreads();

  for (int ti = wave; ti < 8; ti += 4) {
    floatx4 acc = (floatx4)0.f;
    #pragma unroll
    for (int k0 = 0; k0 < 192; k0 += 32) {
      bf16x8 afr = *(const bf16x8*)&sqln[ln15 * 200 + k0 + kg * 8];
      bf16x8 bfr = *(const bf16x8*)&wbq[((size_t)(ti * 16 + ln15)) * 192 + k0 + kg * 8];
      acc = __builtin_amdgcn_mfma_f32_16x16x32_bf16(afr, bfr, acc, 0, 0, 0);
    }
    #pragma unroll
    for (int r = 0; r < 4; ++r)
      sqpF[(kg * 4 + r) * 132 + ti * 16 + ln15] = acc[r];
  }
  __syncthreads();

  {
    float S0v = *sS0;
    int qq = tid >> 4, kc = tid & 15;
    const float4* w4 = (const float4*)swm;
    const float4* q4 = (const float4*)&sqpF[qq * 132];
    const float4* ka = (const float4*)&skp[kc * 132];
    const float4* kb = (const float4*)&skp[(kc + 16) * 132];
    float acc0 = S0v, acc1 = S0v;
    #pragma unroll 8
    for (int d4 = 0; d4 < 32; ++d4) {
      float4 qv = q4[d4], k0v = ka[d4], k1v = kb[d4], wv = w4[d4];
      acc0 += wv.x * RCPF(EXP2F(qv.x + k0v.x) + 1.f);
      acc0 += wv.y * RCPF(EXP2F(qv.y + k0v.y) + 1.f);
      acc0 += wv.z * RCPF(EXP2F(qv.z + k0v.z) + 1.f);
      acc0 += wv.w * RCPF(EXP2F(qv.w + k0v.w) + 1.f);
      acc1 += wv.x * RCPF(EXP2F(qv.x + k1v.x) + 1.f);
      acc1 += wv.y * RCPF(EXP2F(qv.y + k1v.y) + 1.f);
      acc1 += wv.z * RCPF(EXP2F(qv.z + k1v.z) + 1.f);
      acc1 += wv.w * RCPF(EXP2F(qv.w + k1v.w) + 1.f);
    }
    float mx = fmaxf(acc0, acc1);
    #pragma unroll
    for (int off = 8; off; off >>= 1) mx = fmaxf(mx, __shfl_xor(mx, off));
    float e0 = __expf(acc0 - mx), e1 = __expf(acc1 - mx);
    float s = e0 + e1;
    #pragma unroll
    for (int off = 8; off; off >>= 1) s += __shfl_xor(s, off);
    float inv = 1.f / s;
    se[qq * 36 + kc]      = e0 * inv;
    se[qq * 36 + kc + 16] = e1 * inv;
  }
  __syncthreads();

  {
    float4 a0 = *(const float4*)&se[ln15 * 36 + kg * 8];
    float4 a1 = *(const float4*)&se[ln15 * 36 + kg * 8 + 4];
    ushort8v au;
    au[0] = f2bf(a0.x); au[1] = f2bf(a0.y); au[2] = f2bf(a0.z); au[3] = f2bf(a0.w);
    au[4] = f2bf(a1.x); au[5] = f2bf(a1.y); au[6] = f2bf(a1.z); au[7] = f2bf(a1.w);
    for (int ti = wave; ti < 12; ti += 4) {
      bf16x8 bfr = *(const bf16x8*)&vT[((size_t)(b * 192 + ti * 16 + ln15)) * 32 + kg * 8];
      floatx4 acc = __builtin_amdgcn_mfma_f32_16x16x32_bf16(
          __builtin_bit_cast(bf16x8, au), bfr, (floatx4)0.f, 0, 0, 0);
      #pragma unroll
      for (int r = 0; r < 4; ++r)
        sctx[(kg * 4 + r) * 200 + ti * 16 + ln15] = f2bf(acc[r]);
    }
  }
  __syncthreads();

  for (int ti = wave; ti < 12; ti += 4) {
    floatx4 acc = (floatx4)0.f;
    #pragma unroll
    for (int k0 = 0; k0 < 192; k0 += 32) {
      bf16x8 afr = *(const bf16x8*)&sctx[ln15 * 200 + k0 + kg * 8];
      bf16x8 bfr = *(const bf16x8*)&wbo[((size_t)(ti * 16 + ln15)) * 192 + k0 + kg * 8];
      acc = __builtin_amdgcn_mfma_f32_16x16x32_bf16(afr, bfr, acc, 0, 0, 0);
    }
    float bv = out_b[ti * 16 + ln15];
    #pragma unroll
    for (int r = 0; r < 4; ++r)
      sf[(kg * 4 + r) * 193 + ti * 16 + ln15] = acc[r] + bv;
  }
  __syncthreads();

  #pragma unroll
  for (int i = 0; i < 4; ++i) {
    int rr = wave + i * 4;
    float v0 = sf[rr * 193 + lane]       + qreg[i][0];
    float v1 = sf[rr * 193 + lane + 64]  + qreg[i][1];
    float v2 = sf[rr * 193 + lane + 128] + qreg[i][2];
    float t_s = v0 + v1 + v2;
    float t_s2 = v0 * v0 + v1 * v1 + v2 * v2;
    #pragma unroll
    for (int off = 32; off; off >>= 1) { t_s += __shfl_xor(t_s, off); t_s2 += __shfl_xor(t_s2, off); }
    float m2 = t_s * (1.f / 192.f);
    float var2 = t_s2 * (1.f / 192.f) - m2 * m2;
    float inv2 = rsqrtf(var2 + 1e-5f);
    sf[rr * 193 + lane]       = (v0 - m2) * inv2 * ln_out_w[lane]       + ln_out_b[lane];
    sf[rr * 193 + lane + 64]  = (v1 - m2) * inv2 * ln_out_w[lane + 64]  + ln_out_b[lane + 64];
    sf[rr * 193 + lane + 128] = (v2 - m2) * inv2 * ln_out_w[lane + 128] + ln_out_b[lane + 128];
  }
  __syncthreads();

  for (int j = tid; j < 768; j += 256) {
    int m = j >> 2, t4 = j & 3;
    float4 o4;
    o4.x = sf[(t4 * 4 + 0) * 193 + m];
    o4.y = sf[(t4 * 4 + 1) * 193 + m];
    o4.z = sf[(t4 * 4 + 2) * 193 + m];
    o4.w = sf[(t4 * 4 + 3) * 193 + m];
    *(float4*)&out[((size_t)(b * 192 + m)) * 256 + t0 + t4 * 4] = o4;
  }
}

// ---------------------------------------------------------------------------
extern "C" void kernel_launch(void* const* d_in, const int* in_sizes, int n_in,
                              void* d_out, int out_size, void* d_ws, size_t ws_size,
                              hipStream_t stream) {
  (void)in_sizes; (void)n_in; (void)out_size; (void)ws_size;
  const float* x_p     = (const float*)d_in[0];
  const float* y_g     = (const float*)d_in[1];
  const float* conv1_w = (const float*)d_in[2];
  const float* conv1_b = (const float*)d_in[3];
  const float* gamma1  = (const float*)d_in[4];
  const float* beta1   = (const float*)d_in[5];
  const float* conv2_w = (const float*)d_in[6];
  const float* conv2_b = (const float*)d_in[7];
  const float* gamma2  = (const float*)d_in[8];
  const float* beta2   = (const float*)d_in[9];
  const float* conv3_w = (const float*)d_in[10];
  const float* conv3_b = (const float*)d_in[11];
  const float* ln_q_w  = (const float*)d_in[12];
  const float* ln_q_b  = (const float*)d_in[13];
  const float* ln_kv_w = (const float*)d_in[14];
  const float* ln_kv_b = (const float*)d_in[15];
  const float* ln_out_w= (const float*)d_in[16];
  const float* ln_out_b= (const float*)d_in[17];
  const float* Wq      = (const float*)d_in[18];
  const float* Wk      = (const float*)d_in[19];
  const float* v_w     = (const float*)d_in[20];
  const float* Wv      = (const float*)d_in[21];
  const float* out_w   = (const float*)d_in[22];
  const float* out_b   = (const float*)d_in[23];
  float* out = (float*)d_out;
  float* ws  = (float*)d_ws;

  ushortT* x2bf  = (ushortT*)(ws + OFF_X2BF);
  ushortT* x3bf  = (ushortT*)(ws + OFF_X3BF);
  ushortT* qrawb = (ushortT*)(ws + OFF_QRAW);
  ushortT* wbq   = (ushortT*)(ws + OFF_WBQ);
  ushortT* wbk   = (ushortT*)(ws + OFF_WBK);
  ushortT* wbv   = (ushortT*)(ws + OFF_WBV);
  ushortT* wbo   = (ushortT*)(ws + OFF_WBO);
  ushortT* wt2   = (ushortT*)(ws + OFF_WT2);
  ushortT* wt3   = (ushortT*)(ws + OFF_WT3);
  ushortT* wc1   = (ushortT*)(ws + OFF_WC1);
  ushortT* gb1   = (ushortT*)(ws + OFF_GB1);
  ushortT* gb2   = (ushortT*)(ws + OFF_GB2);
  float*   kp    = (float*)(ws + OFF_KP);
  ushortT* vTb   = (ushortT*)(ws + OFF_VT);

  prep_kernel<<<3152, 256, 0, stream>>>(conv2_w, wt2, conv3_w, wt3, conv1_w, wc1,
                                        Wq, wbq, Wk, wbk, Wv, wbv, out_w, wbo,
                                        gamma1, gb1, gamma2, gb2);
  conv1_kv_kernel<<<576, 256, 0, stream>>>(x_p, wc1, conv1_b, gb1, beta1, x2bf,
                                           y_g, ln_kv_w, ln_kv_b, wbk, wbv,
                                           kp, vTb);
  conv2_gdn_kernel<<<256, 512, 0, stream>>>(x2bf, wt2, conv2_b, gb2, beta2, x3bf);
  conv3_mfma_kernel<<<768, 256, 0, stream>>>(x3bf, wt3, conv3_b, qrawb);
  attn_kernel<<<1024, 256, 0, stream>>>(qrawb, ln_q_w, ln_q_b, kp, vTb,
                                        wbq, wbo, v_w, out_b, ln_out_w,
                                        ln_out_b, out);
}